// Round 20
// baseline (477.953 us; speedup 1.0000x reference)
//
#include <hip/hip_runtime.h>
#include <hip/hip_bf16.h>

// CDC conv: out = conv3x3(x,W,zero-pad) + b - 0.7 * laplacian(channel_sum(x), edge-pad)
// fp8 e4m3 MX-scaled MFMA implicit GEMM, fp32 epilogue. Round 20: FUSED —
// transpose pass deleted; each conv block loads its 3 x-rows directly
// (512B-contiguous NCHW rows, coalesced gload_lds), converts f32->fp8 granules
// in-block (cvt_pk_fp8_f32), and computes its 3 s-rows in LDS. Deletes a
// 328MB HBM pass (~63us). K-split xs (R16 layout, correctness-proven) keeps
// LDS at 24,960 + 16,384(tile) + 1,536(srow) = 42,880B -> 3 blocks/CU; compute
// is R15's exact (256,3)/64-AGPR no-spill shape. 12 stage-phases x 2 barriers
// + 2 = 26 barriers/block, overlapped across 3 blocks/CU.
// ws: [0,144KB) W_packed [tap][kp:4][kb:2][co:128][16B] fp8 (x16 scaled).

typedef __attribute__((ext_vector_type(8))) int int8v;
typedef __attribute__((ext_vector_type(16))) float f32x16;

#define THETA 0.7f

// f32 -> OCP e4m3fn, RNE (normal), saturate, subnormal-correct. (pack_w only)
__device__ __forceinline__ unsigned f2e4m3(float x) {
  unsigned u = __builtin_bit_cast(unsigned, x);
  unsigned s = (u >> 24) & 0x80u;
  unsigned au = u & 0x7FFFFFFFu;
  if (au >= 0x43E80000u) return s | 0x7Eu;        // |x| >= 464 -> 448
  if (au < 0x3C800000u) {                          // |x| < 2^-6 -> subnormal
    float q = __builtin_bit_cast(float, au) * 512.0f;   // / 2^-9
    return s | (unsigned)(int)(q + 0.5f);          // 0..8 (8 == min normal)
  }
  unsigned m = au + 0x000FFFFFu + ((au >> 20) & 1u);    // RNE at bit 20
  int e = (int)(m >> 23) - 127;
  unsigned mant = (m >> 20) & 7u;
  if (e > 8 || (e == 8 && mant == 7u)) return s | 0x7Eu;
  return s | ((unsigned)(e + 7) << 3) | mant;
}

__device__ __forceinline__ void gload_lds16(const void* g, void* l) {
  __builtin_amdgcn_global_load_lds(
      (const __attribute__((address_space(1))) unsigned int*)g,
      (__attribute__((address_space(3))) unsigned int*)l, 16, 0, 0);
}

// ---- pack W[co][ci][3][3] f32 -> wp[tap][kp:4][kb:2][co:128][16B] fp8 (x16)
// granule bytes: [0..7] = ci=kp*32+kb*8+j, [8..15] = ci=kp*32+16+kb*8+j
__global__ void pack_w_kernel(const float* __restrict__ w, char* __restrict__ wp) {
  const int co = blockIdx.x, ci = threadIdx.x;
  const float* src = w + ((size_t)co * 128 + ci) * 9;
  const int kp = ci >> 5, r = ci & 31;
  const int half = (r >> 4) & 1, kb = (r >> 3) & 1, j = r & 7;
  #pragma unroll
  for (int tap = 0; tap < 9; ++tap) {
    const unsigned char bv = (unsigned char)f2e4m3(src[tap] * 16.0f);
    wp[(size_t)((tap * 4 + kp) * 2 + kb) * 2048 + co * 16 + half * 8 + j] = bv;
  }
}

// ---- fused conv: 4 waves; block 128co x 128w x 1h; MX fp8 32x32x64
__global__ __launch_bounds__(256, 3)
void conv_mfma_kernel(const float* __restrict__ x, const char* __restrict__ wp,
                      const float* __restrict__ bias, float* __restrict__ out) {
  // K-half fp8 staging: 3 rows x 4 chunks x 130 granules x 16B = 24,960B
  __shared__ uint4 xs4[3 * 4 * 130];
  __shared__ float tile[32][128];     // 16,384B f32 stage (one kp x one row)
  __shared__ float srow[3][128];      // 1,536B channel-sums of rows h-1..h+1
  char* xs = (char*)xs4;

  // bijective XCD swizzle: 4096 blocks, 8 XCDs, 512 contiguous per XCD;
  // consecutive h on one XCD share 2/3 x-rows -> L2 hits.
  const int bid = blockIdx.x;
  const int sw = (bid & 7) * 512 + (bid >> 3);
  const int h = sw & 127;
  const int b = sw >> 7;

  const int t = threadIdx.x;
  const int lane = t & 63, wave = t >> 6;
  const int wm = wave >> 1, wn = wave & 1;
  const int l31 = lane & 31, kb = lane >> 5;

  f32x16 acc[2][2];
  #pragma unroll
  for (int mt = 0; mt < 2; ++mt)
    #pragma unroll
    for (int nt = 0; nt < 2; ++nt)
      #pragma unroll
      for (int r = 0; r < 16; ++r)
        acc[mt][nt][r] = 0.f;

  // zero w-borders (gi 0/129 of each chunk; conv zero-pads w) + srow init
  if (t < 24) {
    const int row = t >> 3, k = t & 7, c = k >> 1, side = k & 1;
    xs4[(row * 4 + c) * 130 + side * 129] = make_uint4(0u, 0u, 0u, 0u);
  }
  if (t < 128) { srow[0][t] = 0.f; srow[1][t] = 0.f; srow[2][t] = 0.f; }

  const char* xb = (const char*)x;

  #pragma unroll
  for (int kp2 = 0; kp2 < 2; ++kp2) {
    // ---- stage + convert 6 tile-phases (3 rows x 2 kp) for this K-half
    #pragma unroll
    for (int r = 0; r < 3; ++r) {
      const int hh = h - 1 + r;
      const bool inb = (unsigned)hh < 128u;
      #pragma unroll
      for (int kpl = 0; kpl < 2; ++kpl) {
        const int kp = kp2 * 2 + kpl;
        __syncthreads();             // tile free (prev convert done / compute0 passed)
        if (inb) {                   // block-uniform
          #pragma unroll
          for (int i = 0; i < 4; ++i) {
            const int u = i * 256 + t;       // 0..1023 16B granules
            const int ci = u >> 5, wq = (u & 31) << 2;
            gload_lds16(xb + ((((size_t)(b * 128 + kp * 32 + ci) * 128 + hh) * 128 + wq) * 4),
                        (char*)tile + (size_t)u * 16);
          }
        }
        __syncthreads();             // tile ready (barrier drains vmcnt)
        // convert: thread -> granule (c_l = chunk within kp, w)
        const int c_l = t >> 7, w = t & 127;
        unsigned wd[4];
        if (inb) {
          #pragma unroll
          for (int half = 0; half < 2; ++half) {
            const int b0 = half * 16 + c_l * 8;
            int lo = __builtin_amdgcn_cvt_pk_fp8_f32(tile[b0 + 0][w], tile[b0 + 1][w], 0, false);
            lo = __builtin_amdgcn_cvt_pk_fp8_f32(tile[b0 + 2][w], tile[b0 + 3][w], lo, true);
            int hi = __builtin_amdgcn_cvt_pk_fp8_f32(tile[b0 + 4][w], tile[b0 + 5][w], 0, false);
            hi = __builtin_amdgcn_cvt_pk_fp8_f32(tile[b0 + 6][w], tile[b0 + 7][w], hi, true);
            wd[half * 2] = (unsigned)lo; wd[half * 2 + 1] = (unsigned)hi;
          }
          if (t < 128) {             // channel-sum partial for this 32-ci slab
            float a = 0.f;
            #pragma unroll 8
            for (int j = 0; j < 32; ++j) a += tile[j][t];
            srow[r][t] += a;
          }
        } else {
          wd[0] = wd[1] = wd[2] = wd[3] = 0u;
        }
        xs4[(r * 4 + kpl * 2 + c_l) * 130 + 1 + w] =
            make_uint4(wd[0], wd[1], wd[2], wd[3]);
      }
    }
    __syncthreads();                 // xs (and srow) ready for compute

    // ---- compute this K-half (R15 shape: 4 MFMAs per (kh,dxi))
    #pragma unroll
    for (int kh = 0; kh < 3; ++kh) {
      const char* xrow = xs + (size_t)kh * 4 * 130 * 16;
      #pragma unroll
      for (int dxi = 0; dxi < 3; ++dxi) {
        const int tap = kh * 3 + dxi;
        const char* wb = wp + (size_t)(tap * 8 + kp2 * 4 + kb * 2) * 2048;
        int8v av[2];
        #pragma unroll
        for (int mt = 0; mt < 2; ++mt) {
          const uint4 lo = *(const uint4*)(wb + (wm * 64 + mt * 32 + l31) * 16);
          const uint4 hi = *(const uint4*)(wb + 2048 + (wm * 64 + mt * 32 + l31) * 16);
          av[mt] = (int8v){(int)lo.x, (int)lo.y, (int)lo.z, (int)lo.w,
                           (int)hi.x, (int)hi.y, (int)hi.z, (int)hi.w};
        }
        const int c0 = kb * 2;       // local chunk pair for this lane-half
        int8v bv[2];
        #pragma unroll
        for (int nt = 0; nt < 2; ++nt) {
          const int gi = wn * 64 + nt * 32 + l31 + dxi;   // borders populated
          const uint4 lo = *(const uint4*)(xrow + (size_t)(c0 * 130 + gi) * 16);
          const uint4 hi = *(const uint4*)(xrow + (size_t)((c0 + 1) * 130 + gi) * 16);
          bv[nt] = (int8v){(int)lo.x, (int)lo.y, (int)lo.z, (int)lo.w,
                           (int)hi.x, (int)hi.y, (int)hi.z, (int)hi.w};
        }
        #pragma unroll
        for (int mt = 0; mt < 2; ++mt)
          #pragma unroll
          for (int nt = 0; nt < 2; ++nt)
            acc[mt][nt] = __builtin_amdgcn_mfma_scale_f32_32x32x64_f8f6f4(
                av[mt], bv[nt], acc[mt][nt],
                0 /*cbsz: fp8 e4m3*/, 0 /*blgp: fp8 e4m3*/,
                0, 0x7F7F7F7Fu /*scale_a = 1.0*/,
                0, 0x7F7F7F7Fu /*scale_b = 1.0*/);
      }
    }
  }

  // epilogue: stencil from in-block srow (edge-replicate via index clamp)
  float dif[2];
  #pragma unroll
  for (int nt = 0; nt < 2; ++nt) {
    const int w = wn * 64 + nt * 32 + l31;
    const float up = srow[h > 0 ? 0 : 1][w];
    const float dn = srow[h < 127 ? 2 : 1][w];
    const float lf = srow[1][w > 0 ? w - 1 : 0];
    const float rt = srow[1][w < 127 ? w + 1 : 127];
    dif[nt] = up + dn + lf + rt - 4.0f * srow[1][w];
  }
  // 32x32 C/D layout (m74/m101, shape-determined m121-128):
  // col=lane&31, row=(r&3)+8*(r>>2)+4*(lane>>5)
  #pragma unroll
  for (int mt = 0; mt < 2; ++mt) {
    #pragma unroll
    for (int r = 0; r < 16; ++r) {
      const int co = wm * 64 + mt * 32 + (r & 3) + 8 * (r >> 2) + 4 * kb;
      const float bvl = bias[co];
      float* orow = out + ((size_t)(b * 128 + co) * 128 + h) * 128;
      #pragma unroll
      for (int nt = 0; nt < 2; ++nt) {
        const int w = wn * 64 + nt * 32 + l31;
        orow[w] = acc[mt][nt][r] * 0.0625f + bvl - THETA * dif[nt];
      }
    }
  }
}

extern "C" void kernel_launch(void* const* d_in, const int* in_sizes, int n_in,
                              void* d_out, int out_size, void* d_ws, size_t ws_size,
                              hipStream_t stream) {
  const float* x = (const float*)d_in[0];
  const float* W = (const float*)d_in[1];
  const float* bias = (const float*)d_in[2];
  float* out = (float*)d_out;
  char* wp = (char*)d_ws;            // 147,456 B of W_packed
  pack_w_kernel<<<dim3(128), dim3(128), 0, stream>>>(W, wp);
  conv_mfma_kernel<<<dim3(4096), dim3(256), 0, stream>>>(x, wp, bias, out);
}

// Round 21
// 187.278 us; speedup vs baseline: 2.5521x; 2.5521x over previous
//
#include <hip/hip_runtime.h>
#include <hip/hip_bf16.h>

// CDC conv: out = conv3x3(x,W,zero-pad) + b - 0.7 * laplacian(channel_sum(x), edge-pad)
// fp8 e4m3 MX-scaled MFMA implicit GEMM (9 tap-GEMMs, K=Cin), fp32 epilogue.
// FINAL (= R15, session best 187.6us): 3-kernel pipeline.
//  pack_w (~3us): W -> fp8 x16, [tap][kp:4][kb:2][co:128][16B].
//  transpose_sum (~63us, HBM floor): x f32 -> x_t fp8 ci-major granules + s.
//  conv (~121us): block 128co x 128w x 1h, 4 waves, (256,3) no-spill envelope
//  (4 waves/SIMD spills structurally: 6/6 attempts, unified-file quantization),
//  full-K 48KB LDS w-border-padded, ONE barrier, W L1-broadcast,
//  mfma_scale_f32_32x32x64_f8f6f4 (scale=1.0, 2.14x non-scaled fp8 rate;
//  A/B share k-permutation inside each 64-k scope -> exact), XCD swizzle.
// ws: [0,64MB) x_t fp8 [b][h][kp:4][kb:2][w:128][16B], [128MB,+144KB) W_packed
// (x16 scaled), then s[b][h][w] f32 (8MB).

typedef __attribute__((ext_vector_type(8))) int int8v;
typedef __attribute__((ext_vector_type(16))) float f32x16;

#define THETA 0.7f
#define XT_OFF   0
#define WP_OFF   134217728ull
#define S_OFF    (134217728ull + 294912ull)

// f32 -> OCP e4m3fn, RNE (normal), saturate, subnormal-correct. (pack_w only)
__device__ __forceinline__ unsigned f2e4m3(float x) {
  unsigned u = __builtin_bit_cast(unsigned, x);
  unsigned s = (u >> 24) & 0x80u;
  unsigned au = u & 0x7FFFFFFFu;
  if (au >= 0x43E80000u) return s | 0x7Eu;        // |x| >= 464 -> 448
  if (au < 0x3C800000u) {                          // |x| < 2^-6 -> subnormal
    float q = __builtin_bit_cast(float, au) * 512.0f;   // / 2^-9
    return s | (unsigned)(int)(q + 0.5f);          // 0..8 (8 == min normal)
  }
  unsigned m = au + 0x000FFFFFu + ((au >> 20) & 1u);    // RNE at bit 20
  int e = (int)(m >> 23) - 127;
  unsigned mant = (m >> 20) & 7u;
  if (e > 8 || (e == 8 && mant == 7u)) return s | 0x7Eu;
  return s | ((unsigned)(e + 7) << 3) | mant;
}

__device__ __forceinline__ void gload_lds16(const void* g, void* l) {
  __builtin_amdgcn_global_load_lds(
      (const __attribute__((address_space(1))) unsigned int*)g,
      (__attribute__((address_space(3))) unsigned int*)l, 16, 0, 0);
}

// ---- pack W[co][ci][3][3] f32 -> wp[tap][kp:4][kb:2][co:128][16B] fp8 (x16)
// granule bytes: [0..7] = k=kp*32+kb*8+j (ks=2kp), [8..15] = k=kp*32+16+kb*8+j
__global__ void pack_w_kernel(const float* __restrict__ w, char* __restrict__ wp) {
  const int co = blockIdx.x, ci = threadIdx.x;
  const float* src = w + ((size_t)co * 128 + ci) * 9;
  const int kp = ci >> 5, r = ci & 31;
  const int half = (r >> 4) & 1, kb = (r >> 3) & 1, j = r & 7;
  #pragma unroll
  for (int tap = 0; tap < 9; ++tap) {
    const unsigned char bv = (unsigned char)f2e4m3(src[tap] * 16.0f);
    wp[(size_t)((tap * 4 + kp) * 2 + kb) * 2048 + co * 16 + half * 8 + j] = bv;
  }
}

// ---- x f32 -> x_t fp8 [b][h][kp:4][kb:2][w:128][16B] + s[b][h][w] = sum_ci x
// Two 64-ci phases; 34KB LDS -> 4 blocks/CU.
__global__ __launch_bounds__(256)
void transpose_sum_kernel(const float* __restrict__ x, char* __restrict__ xt,
                          float* __restrict__ s) {
  __shared__ float tile[64][129];     // 33,024 B
  __shared__ float s2[2][128];        // 1,024 B
  const int h = blockIdx.x, b = blockIdx.y;
  const int t = threadIdx.x;
  s2[t >> 7][t & 127] = 0.f;
  char* rowb = xt + (size_t)(b * 128 + h) * 16384;

  #pragma unroll
  for (int p = 0; p < 2; ++p) {
    __syncthreads();                  // tile free (prev phase read) + s2 init done
    {
      const int ciq = t >> 5;         // 0..7
      const int wq = (t & 31) << 2;   // 0..124
      #pragma unroll
      for (int i = 0; i < 8; ++i) {
        const int cil = i * 8 + ciq;  // 0..63
        const int ci = p * 64 + cil;
        const float4 v = *(const float4*)(x + (((size_t)(b * 128 + ci) * 128 + h) * 128 + wq));
        tile[cil][wq] = v.x; tile[cil][wq + 1] = v.y;
        tile[cil][wq + 2] = v.z; tile[cil][wq + 3] = v.w;
      }
    }
    __syncthreads();
    {
      const int w = t & 127, hseg = t >> 7;
      float a = 0.f;
      #pragma unroll 8
      for (int j = 0; j < 32; ++j) a += tile[hseg * 32 + j][w];
      s2[hseg][w] += a;               // (hseg,w) owned by this thread
    }
    // granule writes: 512 granules this phase (chunks p*4 .. p*4+3)
    #pragma unroll
    for (int i = 0; i < 2; ++i) {
      const int u = i * 256 + t;      // 0..511
      const int lc = u >> 7;          // local chunk 0..3
      const int w = u & 127;
      const int base = (lc >> 1) * 32 + (lc & 1) * 8;  // ci_local of byte 0
      unsigned wd[4];
      #pragma unroll
      for (int half = 0; half < 2; ++half) {
        const int c0 = base + half * 16;
        int lo = __builtin_amdgcn_cvt_pk_fp8_f32(tile[c0 + 0][w], tile[c0 + 1][w], 0, false);
        lo = __builtin_amdgcn_cvt_pk_fp8_f32(tile[c0 + 2][w], tile[c0 + 3][w], lo, true);
        int hi = __builtin_amdgcn_cvt_pk_fp8_f32(tile[c0 + 4][w], tile[c0 + 5][w], 0, false);
        hi = __builtin_amdgcn_cvt_pk_fp8_f32(tile[c0 + 6][w], tile[c0 + 7][w], hi, true);
        wd[half * 2] = (unsigned)lo; wd[half * 2 + 1] = (unsigned)hi;
      }
      *(uint4*)(rowb + (size_t)(p * 512 + u) * 16) = make_uint4(wd[0], wd[1], wd[2], wd[3]);
    }
  }
  __syncthreads();
  if (t < 128) s[(size_t)(b * 128 + h) * 128 + t] = s2[0][t] + s2[1][t];
}

// ---- conv: 4 waves; block 128co x 128w x 1h; MX fp8 32x32x64; padded LDS
__global__ __launch_bounds__(256, 3)
void conv_mfma_kernel(const char* __restrict__ xt, const char* __restrict__ wp,
                      const float* __restrict__ bias, const float* __restrict__ s,
                      float* __restrict__ out) {
  // 3 rows x 8 kchunks x 130 granules x 16B = 49,920B; granule 0 and 129 of
  // each chunk are zero borders (w=-1 / w=128) -> unconditional bv reads.
  __shared__ uint4 xs4[3 * 8 * 130];
  char* xs = (char*)xs4;

  // bijective XCD swizzle: 4096 blocks, 8 XCDs, 512 contiguous per XCD.
  const int bid = blockIdx.x;
  const int sw = (bid & 7) * 512 + (bid >> 3);
  const int h = sw & 127;
  const int b = sw >> 7;

  const int t = threadIdx.x;
  const int lane = t & 63, wave = t >> 6;
  const int wm = wave >> 1, wn = wave & 1;
  const int l31 = lane & 31, kb = lane >> 5;

  f32x16 acc[2][2];
  #pragma unroll
  for (int mt = 0; mt < 2; ++mt)
    #pragma unroll
    for (int nt = 0; nt < 2; ++nt)
      #pragma unroll
      for (int r = 0; r < 16; ++r)
        acc[mt][nt][r] = 0.f;

  // zero borders: 3 rows x 8 chunks x 2 sides = 48 granules
  if (t < 48) {
    const int row = t >> 4, k = t & 15, chunk = k >> 1, side = k & 1;
    xs4[row * 1040 + chunk * 130 + side * 129] = make_uint4(0u, 0u, 0u, 0u);
  }
  // stage all 3 input rows (full K), linear global -> padded LDS
  #pragma unroll
  for (int r = 0; r < 3; ++r) {
    const int hh = h - 1 + r;
    if ((unsigned)hh < 128u) {
      const char* rb = xt + (size_t)(b * 128 + hh) * 16384;
      #pragma unroll
      for (int i = 0; i < 4; ++i) {
        const int u = i * 256 + t;          // 0..1023
        const int chunk = u >> 7, w = u & 127;
        gload_lds16(rb + (size_t)u * 16,
                    xs + (size_t)(r * 1040 + chunk * 130 + 1 + w) * 16);
      }
    } else {
      #pragma unroll
      for (int i = 0; i < 5; ++i) {
        const int u = i * 256 + t;
        if (u < 1040) xs4[r * 1040 + u] = make_uint4(0u, 0u, 0u, 0u);
      }
    }
  }
  __syncthreads();                 // the ONLY barrier

  #pragma unroll
  for (int kh = 0; kh < 3; ++kh) {
    const char* xrow = xs + kh * 16640;  // input row h-1+kh
    #pragma unroll
    for (int dxi = 0; dxi < 3; ++dxi) {
      const int tap = kh * 3 + dxi;
      const char* wb = wp + (size_t)(tap * 8) * 2048;  // 8 chunks of this tap
      #pragma unroll
      for (int kp2 = 0; kp2 < 2; ++kp2) {
        // lane-half kb needs old-kp block kp2*2+kb = its two adjacent granules
        const int c0 = (kp2 * 2 + kb) * 2;
        // A (W): 2 variants/block -> L1 broadcast; 2x b128 -> 32B operand
        int8v av[2];
        #pragma unroll
        for (int mt = 0; mt < 2; ++mt) {
          const uint4 lo = *(const uint4*)(wb + (size_t)c0 * 2048 +
                                           (wm * 64 + mt * 32 + l31) * 16);
          const uint4 hi = *(const uint4*)(wb + (size_t)(c0 + 1) * 2048 +
                                           (wm * 64 + mt * 32 + l31) * 16);
          av[mt] = (int8v){(int)lo.x, (int)lo.y, (int)lo.z, (int)lo.w,
                           (int)hi.x, (int)hi.y, (int)hi.z, (int)hi.w};
        }
        // B (X) from LDS: unconditional (borders zero); same k-permutation as A
        int8v bv[2];
        #pragma unroll
        for (int nt = 0; nt < 2; ++nt) {
          const int g = wn * 64 + nt * 32 + l31 + dxi;   // border +1 and dx -1 cancel
          const uint4 lo = *(const uint4*)(xrow + (size_t)(c0 * 130 + g) * 16);
          const uint4 hi = *(const uint4*)(xrow + (size_t)((c0 + 1) * 130 + g) * 16);
          bv[nt] = (int8v){(int)lo.x, (int)lo.y, (int)lo.z, (int)lo.w,
                           (int)hi.x, (int)hi.y, (int)hi.z, (int)hi.w};
        }
        #pragma unroll
        for (int mt = 0; mt < 2; ++mt)
          #pragma unroll
          for (int nt = 0; nt < 2; ++nt)
            acc[mt][nt] = __builtin_amdgcn_mfma_scale_f32_32x32x64_f8f6f4(
                av[mt], bv[nt], acc[mt][nt],
                0 /*cbsz: fp8 e4m3*/, 0 /*blgp: fp8 e4m3*/,
                0, 0x7F7F7F7Fu /*scale_a = 1.0*/,
                0, 0x7F7F7F7Fu /*scale_b = 1.0*/);
      }
    }
  }

  // epilogue: per-thread fp32 stencil from s (L3-resident) + bias; undo W x16
  const float* sb = s + (size_t)b * 16384;
  float dif[2];
  #pragma unroll
  for (int nt = 0; nt < 2; ++nt) {
    const int w = wn * 64 + nt * 32 + l31;
    const float sc = sb[h * 128 + w];
    const float up = sb[(h > 0 ? h - 1 : 0) * 128 + w];
    const float dn = sb[(h < 127 ? h + 1 : 127) * 128 + w];
    const float lf = sb[h * 128 + (w > 0 ? w - 1 : 0)];
    const float rt = sb[h * 128 + (w < 127 ? w + 1 : 127)];
    dif[nt] = up + dn + lf + rt - 4.0f * sc;
  }
  // 32x32 C/D layout (m74/m101, shape-determined m121-128):
  // col=lane&31, row=(r&3)+8*(r>>2)+4*(lane>>5)
  #pragma unroll
  for (int mt = 0; mt < 2; ++mt) {
    #pragma unroll
    for (int r = 0; r < 16; ++r) {
      const int co = wm * 64 + mt * 32 + (r & 3) + 8 * (r >> 2) + 4 * kb;
      const float bv = bias[co];
      float* orow = out + ((size_t)(b * 128 + co) * 128 + h) * 128;
      #pragma unroll
      for (int nt = 0; nt < 2; ++nt) {
        const int w = wn * 64 + nt * 32 + l31;
        orow[w] = acc[mt][nt][r] * 0.0625f + bv - THETA * dif[nt];
      }
    }
  }
}

extern "C" void kernel_launch(void* const* d_in, const int* in_sizes, int n_in,
                              void* d_out, int out_size, void* d_ws, size_t ws_size,
                              hipStream_t stream) {
  const float* x = (const float*)d_in[0];
  const float* W = (const float*)d_in[1];
  const float* bias = (const float*)d_in[2];
  float* out = (float*)d_out;
  char* ws = (char*)d_ws;
  char* xt = ws + XT_OFF;
  char* wp = ws + WP_OFF;
  float* s = (float*)(ws + S_OFF);
  pack_w_kernel<<<dim3(128), dim3(128), 0, stream>>>(W, wp);
  transpose_sum_kernel<<<dim3(128, 32), dim3(256), 0, stream>>>(x, xt, s);
  conv_mfma_kernel<<<dim3(4096), dim3(256), 0, stream>>>(xt, wp, bias, s, out);
}

// Round 22
// 182.099 us; speedup vs baseline: 2.6247x; 1.0284x over previous
//
#include <hip/hip_runtime.h>
#include <hip/hip_bf16.h>

// CDC conv: out = conv3x3(x,W,zero-pad) + b - 0.7 * laplacian(channel_sum(x), edge-pad)
// fp8 e4m3 MX-scaled MFMA implicit GEMM (9 tap-GEMMs, K=Cin), fp32 epilogue.
// FINAL+micro (R15 + 2 trims): (1) pack_w fused into transpose launch as 128
// extra blocks (by==32; block-uniform branch, no barriers on pack path) —
// saves one dispatch; (2) s_setprio(1) around conv MFMA loop (T5: 3
// independent blocks/CU at different phases = role diversity, attn-like +4-7%).
//  transpose_sum (~63us, 82% HBM BW): x f32 -> x_t fp8 ci-major granules + s.
//  conv (~121us): block 128co x 128w x 1h, 4 waves, (256,3) no-spill envelope
//  (4 waves/SIMD spills structurally: 6/6 attempts), full-K 48KB LDS
//  w-border-padded, ONE barrier, W L1-broadcast, mfma_scale_f32_32x32x64_f8f6f4
//  (scale=1.0; A/B share k-permutation per 64-k scope -> exact), XCD swizzle.
// ws: [0,64MB) x_t fp8 [b][h][kp:4][kb:2][w:128][16B], [128MB,+144KB) W_packed
// (x16 scaled), then s[b][h][w] f32 (8MB).

typedef __attribute__((ext_vector_type(8))) int int8v;
typedef __attribute__((ext_vector_type(16))) float f32x16;

#define THETA 0.7f
#define XT_OFF   0
#define WP_OFF   134217728ull
#define S_OFF    (134217728ull + 294912ull)

// f32 -> OCP e4m3fn, RNE (normal), saturate, subnormal-correct. (pack path only)
__device__ __forceinline__ unsigned f2e4m3(float x) {
  unsigned u = __builtin_bit_cast(unsigned, x);
  unsigned s = (u >> 24) & 0x80u;
  unsigned au = u & 0x7FFFFFFFu;
  if (au >= 0x43E80000u) return s | 0x7Eu;        // |x| >= 464 -> 448
  if (au < 0x3C800000u) {                          // |x| < 2^-6 -> subnormal
    float q = __builtin_bit_cast(float, au) * 512.0f;   // / 2^-9
    return s | (unsigned)(int)(q + 0.5f);          // 0..8 (8 == min normal)
  }
  unsigned m = au + 0x000FFFFFu + ((au >> 20) & 1u);    // RNE at bit 20
  int e = (int)(m >> 23) - 127;
  unsigned mant = (m >> 20) & 7u;
  if (e > 8 || (e == 8 && mant == 7u)) return s | 0x7Eu;
  return s | ((unsigned)(e + 7) << 3) | mant;
}

__device__ __forceinline__ void gload_lds16(const void* g, void* l) {
  __builtin_amdgcn_global_load_lds(
      (const __attribute__((address_space(1))) unsigned int*)g,
      (__attribute__((address_space(3))) unsigned int*)l, 16, 0, 0);
}

// ---- x f32 -> x_t fp8 [b][h][kp:4][kb:2][w:128][16B] + s[b][h][w] = sum_ci x
// Two 64-ci phases; 34KB LDS -> 4 blocks/CU. Blocks with by==32 instead pack
// W[co][ci][3][3] f32 -> wp[tap][kp:4][kb:2][co:128][16B] fp8 (x16 scaled);
// granule bytes: [0..7] = k=kp*32+kb*8+j, [8..15] = k=kp*32+16+kb*8+j.
__global__ __launch_bounds__(256)
void transpose_sum_kernel(const float* __restrict__ x, char* __restrict__ xt,
                          float* __restrict__ s, const float* __restrict__ w,
                          char* __restrict__ wp) {
  if (blockIdx.y == 32) {            // fused pack_w (block-uniform branch;
    const int co = blockIdx.x;       //  this path executes NO barriers)
    const int t = threadIdx.x;
    if (t < 128) {
      const int ci = t;
      const float* src = w + ((size_t)co * 128 + ci) * 9;
      const int kp = ci >> 5, r = ci & 31;
      const int half = (r >> 4) & 1, kb = (r >> 3) & 1, j = r & 7;
      #pragma unroll
      for (int tap = 0; tap < 9; ++tap) {
        const unsigned char bv = (unsigned char)f2e4m3(src[tap] * 16.0f);
        wp[(size_t)((tap * 4 + kp) * 2 + kb) * 2048 + co * 16 + half * 8 + j] = bv;
      }
    }
    return;
  }

  __shared__ float tile[64][129];     // 33,024 B
  __shared__ float s2[2][128];        // 1,024 B
  const int h = blockIdx.x, b = blockIdx.y;
  const int t = threadIdx.x;
  s2[t >> 7][t & 127] = 0.f;
  char* rowb = xt + (size_t)(b * 128 + h) * 16384;

  #pragma unroll
  for (int p = 0; p < 2; ++p) {
    __syncthreads();                  // tile free (prev phase read) + s2 init done
    {
      const int ciq = t >> 5;         // 0..7
      const int wq = (t & 31) << 2;   // 0..124
      #pragma unroll
      for (int i = 0; i < 8; ++i) {
        const int cil = i * 8 + ciq;  // 0..63
        const int ci = p * 64 + cil;
        const float4 v = *(const float4*)(x + (((size_t)(b * 128 + ci) * 128 + h) * 128 + wq));
        tile[cil][wq] = v.x; tile[cil][wq + 1] = v.y;
        tile[cil][wq + 2] = v.z; tile[cil][wq + 3] = v.w;
      }
    }
    __syncthreads();
    {
      const int w2 = t & 127, hseg = t >> 7;
      float a = 0.f;
      #pragma unroll 8
      for (int j = 0; j < 32; ++j) a += tile[hseg * 32 + j][w2];
      s2[hseg][w2] += a;              // (hseg,w) owned by this thread
    }
    // granule writes: 512 granules this phase (chunks p*4 .. p*4+3)
    #pragma unroll
    for (int i = 0; i < 2; ++i) {
      const int u = i * 256 + t;      // 0..511
      const int lc = u >> 7;          // local chunk 0..3
      const int w2 = u & 127;
      const int base = (lc >> 1) * 32 + (lc & 1) * 8;  // ci_local of byte 0
      unsigned wd[4];
      #pragma unroll
      for (int half = 0; half < 2; ++half) {
        const int c0 = base + half * 16;
        int lo = __builtin_amdgcn_cvt_pk_fp8_f32(tile[c0 + 0][w2], tile[c0 + 1][w2], 0, false);
        lo = __builtin_amdgcn_cvt_pk_fp8_f32(tile[c0 + 2][w2], tile[c0 + 3][w2], lo, true);
        int hi = __builtin_amdgcn_cvt_pk_fp8_f32(tile[c0 + 4][w2], tile[c0 + 5][w2], 0, false);
        hi = __builtin_amdgcn_cvt_pk_fp8_f32(tile[c0 + 6][w2], tile[c0 + 7][w2], hi, true);
        wd[half * 2] = (unsigned)lo; wd[half * 2 + 1] = (unsigned)hi;
      }
      *(uint4*)(rowb + (size_t)(p * 512 + u) * 16) = make_uint4(wd[0], wd[1], wd[2], wd[3]);
    }
  }
  __syncthreads();
  if (t < 128) s[(size_t)(b * 128 + h) * 128 + t] = s2[0][t] + s2[1][t];
}

// ---- conv: 4 waves; block 128co x 128w x 1h; MX fp8 32x32x64; padded LDS
__global__ __launch_bounds__(256, 3)
void conv_mfma_kernel(const char* __restrict__ xt, const char* __restrict__ wp,
                      const float* __restrict__ bias, const float* __restrict__ s,
                      float* __restrict__ out) {
  // 3 rows x 8 kchunks x 130 granules x 16B = 49,920B; granule 0 and 129 of
  // each chunk are zero borders (w=-1 / w=128) -> unconditional bv reads.
  __shared__ uint4 xs4[3 * 8 * 130];
  char* xs = (char*)xs4;

  // bijective XCD swizzle: 4096 blocks, 8 XCDs, 512 contiguous per XCD.
  const int bid = blockIdx.x;
  const int sw = (bid & 7) * 512 + (bid >> 3);
  const int h = sw & 127;
  const int b = sw >> 7;

  const int t = threadIdx.x;
  const int lane = t & 63, wave = t >> 6;
  const int wm = wave >> 1, wn = wave & 1;
  const int l31 = lane & 31, kb = lane >> 5;

  f32x16 acc[2][2];
  #pragma unroll
  for (int mt = 0; mt < 2; ++mt)
    #pragma unroll
    for (int nt = 0; nt < 2; ++nt)
      #pragma unroll
      for (int r = 0; r < 16; ++r)
        acc[mt][nt][r] = 0.f;

  // zero borders: 3 rows x 8 chunks x 2 sides = 48 granules
  if (t < 48) {
    const int row = t >> 4, k = t & 15, chunk = k >> 1, side = k & 1;
    xs4[row * 1040 + chunk * 130 + side * 129] = make_uint4(0u, 0u, 0u, 0u);
  }
  // stage all 3 input rows (full K), linear global -> padded LDS
  #pragma unroll
  for (int r = 0; r < 3; ++r) {
    const int hh = h - 1 + r;
    if ((unsigned)hh < 128u) {
      const char* rb = xt + (size_t)(b * 128 + hh) * 16384;
      #pragma unroll
      for (int i = 0; i < 4; ++i) {
        const int u = i * 256 + t;          // 0..1023
        const int chunk = u >> 7, w = u & 127;
        gload_lds16(rb + (size_t)u * 16,
                    xs + (size_t)(r * 1040 + chunk * 130 + 1 + w) * 16);
      }
    } else {
      #pragma unroll
      for (int i = 0; i < 5; ++i) {
        const int u = i * 256 + t;
        if (u < 1040) xs4[r * 1040 + u] = make_uint4(0u, 0u, 0u, 0u);
      }
    }
  }
  __syncthreads();                 // the ONLY barrier

  __builtin_amdgcn_s_setprio(1);   // T5: favor MFMA waves vs co-resident
                                   // blocks' staging (3 blocks/CU, phase-split)
  #pragma unroll
  for (int kh = 0; kh < 3; ++kh) {
    const char* xrow = xs + kh * 16640;  // input row h-1+kh
    #pragma unroll
    for (int dxi = 0; dxi < 3; ++dxi) {
      const int tap = kh * 3 + dxi;
      const char* wb = wp + (size_t)(tap * 8) * 2048;  // 8 chunks of this tap
      #pragma unroll
      for (int kp2 = 0; kp2 < 2; ++kp2) {
        // lane-half kb needs old-kp block kp2*2+kb = its two adjacent granules
        const int c0 = (kp2 * 2 + kb) * 2;
        // A (W): 2 variants/block -> L1 broadcast; 2x b128 -> 32B operand
        int8v av[2];
        #pragma unroll
        for (int mt = 0; mt < 2; ++mt) {
          const uint4 lo = *(const uint4*)(wb + (size_t)c0 * 2048 +
                                           (wm * 64 + mt * 32 + l31) * 16);
          const uint4 hi = *(const uint4*)(wb + (size_t)(c0 + 1) * 2048 +
                                           (wm * 64 + mt * 32 + l31) * 16);
          av[mt] = (int8v){(int)lo.x, (int)lo.y, (int)lo.z, (int)lo.w,
                           (int)hi.x, (int)hi.y, (int)hi.z, (int)hi.w};
        }
        // B (X) from LDS: unconditional (borders zero); same k-permutation as A
        int8v bv[2];
        #pragma unroll
        for (int nt = 0; nt < 2; ++nt) {
          const int g = wn * 64 + nt * 32 + l31 + dxi;   // border +1 and dx -1 cancel
          const uint4 lo = *(const uint4*)(xrow + (size_t)(c0 * 130 + g) * 16);
          const uint4 hi = *(const uint4*)(xrow + (size_t)((c0 + 1) * 130 + g) * 16);
          bv[nt] = (int8v){(int)lo.x, (int)lo.y, (int)lo.z, (int)lo.w,
                           (int)hi.x, (int)hi.y, (int)hi.z, (int)hi.w};
        }
        #pragma unroll
        for (int mt = 0; mt < 2; ++mt)
          #pragma unroll
          for (int nt = 0; nt < 2; ++nt)
            acc[mt][nt] = __builtin_amdgcn_mfma_scale_f32_32x32x64_f8f6f4(
                av[mt], bv[nt], acc[mt][nt],
                0 /*cbsz: fp8 e4m3*/, 0 /*blgp: fp8 e4m3*/,
                0, 0x7F7F7F7Fu /*scale_a = 1.0*/,
                0, 0x7F7F7F7Fu /*scale_b = 1.0*/);
      }
    }
  }
  __builtin_amdgcn_s_setprio(0);

  // epilogue: per-thread fp32 stencil from s (L3-resident) + bias; undo W x16
  const float* sb = s + (size_t)b * 16384;
  float dif[2];
  #pragma unroll
  for (int nt = 0; nt < 2; ++nt) {
    const int w = wn * 64 + nt * 32 + l31;
    const float sc = sb[h * 128 + w];
    const float up = sb[(h > 0 ? h - 1 : 0) * 128 + w];
    const float dn = sb[(h < 127 ? h + 1 : 127) * 128 + w];
    const float lf = sb[h * 128 + (w > 0 ? w - 1 : 0)];
    const float rt = sb[h * 128 + (w < 127 ? w + 1 : 127)];
    dif[nt] = up + dn + lf + rt - 4.0f * sc;
  }
  // 32x32 C/D layout (m74/m101, shape-determined m121-128):
  // col=lane&31, row=(r&3)+8*(r>>2)+4*(lane>>5)
  #pragma unroll
  for (int mt = 0; mt < 2; ++mt) {
    #pragma unroll
    for (int r = 0; r < 16; ++r) {
      const int co = wm * 64 + mt * 32 + (r & 3) + 8 * (r >> 2) + 4 * kb;
      const float bv = bias[co];
      float* orow = out + ((size_t)(b * 128 + co) * 128 + h) * 128;
      #pragma unroll
      for (int nt = 0; nt < 2; ++nt) {
        const int w = wn * 64 + nt * 32 + l31;
        orow[w] = acc[mt][nt][r] * 0.0625f + bv - THETA * dif[nt];
      }
    }
  }
}

extern "C" void kernel_launch(void* const* d_in, const int* in_sizes, int n_in,
                              void* d_out, int out_size, void* d_ws, size_t ws_size,
                              hipStream_t stream) {
  const float* x = (const float*)d_in[0];
  const float* W = (const float*)d_in[1];
  const float* bias = (const float*)d_in[2];
  float* out = (float*)d_out;
  char* ws = (char*)d_ws;
  char* xt = ws + XT_OFF;
  char* wp = ws + WP_OFF;
  float* s = (float*)(ws + S_OFF);
  // grid y=0..31: transpose batches; y=32: fused W pack (one launch total)
  transpose_sum_kernel<<<dim3(128, 33), dim3(256), 0, stream>>>(x, xt, s, W, wp);
  conv_mfma_kernel<<<dim3(4096), dim3(256), 0, stream>>>(xt, wp, bias, s, out);
}